// Round 5
// baseline (116.121 us; speedup 1.0000x reference)
//
#include <hip/hip_runtime.h>

namespace {
constexpr int Hh = 16;
constexpr int Ll = 1024;
constexpr int Dd = 64;
constexpr int Cc = 64;                   // chunk length
constexpr int NCHUNK = Ll / Cc;          // 16
constexpr int NBLK = Hh * NCHUNK;        // 256 = one per CU
constexpr float PI_HALF = 1.5707963267948966f;
constexpr float EPSV = 1e-6f;
constexpr int S1 = 72;                   // phase-A operand stride (shorts)
constexpr int SA = 200;                  // Aq stride
constexpr int SB = 136;                  // Bk stride
constexpr int SV = 200;                  // Bv stride
constexpr int STATE_E = 128 * 64;        // bf16 elems per chunk state [d][f]
}

typedef __attribute__((ext_vector_type(8))) short short8;
typedef __attribute__((ext_vector_type(4))) float floatx4;

__device__ __forceinline__ unsigned short f2bf(float x) {
    unsigned int u = __float_as_uint(x);
    unsigned int r = u + 0x7fffu + ((u >> 16) & 1u);
    return (unsigned short)(r >> 16);
}
__device__ __forceinline__ float bfhi(unsigned int u) {   // high bf16 of a u32
    return __uint_as_float(u & 0xffff0000u);
}
__device__ __forceinline__ float bflo(unsigned int u) {   // low bf16 of a u32
    return __uint_as_float(u << 16);
}

// XOR swizzle (validated round 4): spreads the strided transpose writes
// across banks while keeping MFMA fragment reads b128.
__device__ __forceinline__ int sw1(int row, int j) {
    return (j & 7) | ((((j >> 3) ^ (row >> 3)) & 7) << 3);
}

__global__ __launch_bounds__(256)
void cf_onekernel(const float* __restrict__ qin, const float* __restrict__ kin,
                  const float* __restrict__ vin, float* __restrict__ out,
                  unsigned int* __restrict__ bar,
                  unsigned short* __restrict__ wskv,
                  unsigned short* __restrict__ wsks) {
    const int c = blockIdx.x, h = blockIdx.y;
    const int tid = threadIdx.x;
    __shared__ unsigned short Ak[128 * S1];   // phase-A A: kf^T [f][j] (swizzled)
    __shared__ unsigned short Bv1[80 * S1];   // phase-A B: [V|1]^T [n][j] (swizzled)
    __shared__ unsigned short Aq[64 * SA];    // [l][0..63 scores | 64..191 qf]
    __shared__ unsigned short Bk[80 * SB];    // [n=j][k=f]; row 64 = ksum; 65..79=0
    __shared__ unsigned short Bv[64 * SV];    // [n=d][0..63 V^T | 64..191 S]

    const int wave = tid >> 6, lane = tid & 63;
    const int lrow = lane & 15, quad = lane >> 4;

    const size_t gbase = ((size_t)h * Ll + (size_t)c * Cc) * Dd;
    const float4* q4 = (const float4*)(qin + gbase);
    const float4* k4 = (const float4*)(kin + gbase);
    const float4* v4 = (const float4*)(vin + gbase);

    // ---- stage own chunk: phase-2 operands AND phase-A operands ----
    #pragma unroll
    for (int i = 0; i < 4; ++i) {
        int e4 = i * 256 + tid;
        int j = e4 >> 4, d4 = (e4 & 15) * 4;
        float th = PI_HALF * (float)(c * Cc + j + 1) * (1.0f / (float)Ll);
        float sj, cj;
        __sincosf(th, &sj, &cj);
        float4 qv = q4[e4];
        float q0 = fmaxf(qv.x, 0.f), q1 = fmaxf(qv.y, 0.f);
        float q2 = fmaxf(qv.z, 0.f), q3 = fmaxf(qv.w, 0.f);
        *(ushort4*)&Aq[j * SA + 64 + d4] =
            make_ushort4(f2bf(q0 * sj), f2bf(q1 * sj), f2bf(q2 * sj), f2bf(q3 * sj));
        *(ushort4*)&Aq[j * SA + 128 + d4] =
            make_ushort4(f2bf(q0 * cj), f2bf(q1 * cj), f2bf(q2 * cj), f2bf(q3 * cj));
        float4 kx = k4[e4];
        float k0 = fmaxf(kx.x, 0.f), k1 = fmaxf(kx.y, 0.f);
        float k2 = fmaxf(kx.z, 0.f), k3 = fmaxf(kx.w, 0.f);
        unsigned short ks0 = f2bf(k0 * sj), ks1 = f2bf(k1 * sj);
        unsigned short ks2 = f2bf(k2 * sj), ks3 = f2bf(k3 * sj);
        unsigned short kc0 = f2bf(k0 * cj), kc1 = f2bf(k1 * cj);
        unsigned short kc2 = f2bf(k2 * cj), kc3 = f2bf(k3 * cj);
        *(ushort4*)&Bk[j * SB + d4] = make_ushort4(ks0, ks1, ks2, ks3);
        *(ushort4*)&Bk[j * SB + 64 + d4] = make_ushort4(kc0, kc1, kc2, kc3);
        int col = sw1(d4, j);      // same key for rows d4..d4+3 and 64+d4..+3
        Ak[(d4 + 0) * S1 + col] = ks0;
        Ak[(d4 + 1) * S1 + col] = ks1;
        Ak[(d4 + 2) * S1 + col] = ks2;
        Ak[(d4 + 3) * S1 + col] = ks3;
        Ak[(64 + d4 + 0) * S1 + col] = kc0;
        Ak[(64 + d4 + 1) * S1 + col] = kc1;
        Ak[(64 + d4 + 2) * S1 + col] = kc2;
        Ak[(64 + d4 + 3) * S1 + col] = kc3;
        float4 vx = v4[e4];
        unsigned short v0 = f2bf(vx.x), v1 = f2bf(vx.y);
        unsigned short v2 = f2bf(vx.z), v3 = f2bf(vx.w);
        Bv[(d4 + 0) * SV + j] = v0;
        Bv[(d4 + 1) * SV + j] = v1;
        Bv[(d4 + 2) * SV + j] = v2;
        Bv[(d4 + 3) * SV + j] = v3;
        Bv1[(d4 + 0) * S1 + col] = v0;
        Bv1[(d4 + 1) * S1 + col] = v1;
        Bv1[(d4 + 2) * S1 + col] = v2;
        Bv1[(d4 + 3) * S1 + col] = v3;
    }
    // Bv1 row 64 = ones (key for row 64 is 0 -> unswizzled), rows 65..79 = 0
    if (tid < 64) Bv1[64 * S1 + tid] = 0x3F80;
    if (tid >= 64 && tid < S1) Bv1[64 * S1 + tid] = 0;
    #pragma unroll
    for (int i = 0; i < 3; ++i) {
        int z = i * 256 + tid;
        if (z < (15 * S1) / 2) ((unsigned int*)Bv1)[(65 * S1) / 2 + z] = 0u;
    }
    // zero Bk rows 65..79
    #pragma unroll
    for (int i = 0; i < 4; ++i) {
        int z = i * 256 + tid;
        if (z < (15 * SB) / 2) ((unsigned int*)Bk)[(65 * SB) / 2 + z] = 0u;
    }
    __syncthreads();

    // ---- phase A: own-chunk state GEMM  C[f][d] = kf^T x [V|1] ----
    floatx4 acc[2][5];
    #pragma unroll
    for (int t = 0; t < 2; ++t)
        #pragma unroll
        for (int nt = 0; nt < 5; ++nt)
            acc[t][nt] = (floatx4){0.f, 0.f, 0.f, 0.f};
    #pragma unroll
    for (int t = 0; t < 2; ++t) {
        int fr = (wave * 2 + t) * 16 + lrow;
        int keyA = (fr >> 3) & 7;
        short8 a0 = *(const short8*)&Ak[fr * S1 + ((quad ^ keyA) << 3)];
        short8 a1 = *(const short8*)&Ak[fr * S1 + (((4 + quad) ^ keyA) << 3)];
        #pragma unroll
        for (int nt = 0; nt < 5; ++nt) {
            int nr = nt * 16 + lrow;
            int keyB = (nr >> 3) & 7;
            short8 b0 = *(const short8*)&Bv1[nr * S1 + ((quad ^ keyB) << 3)];
            short8 b1 = *(const short8*)&Bv1[nr * S1 + (((4 + quad) ^ keyB) << 3)];
            acc[t][nt] = __builtin_amdgcn_mfma_f32_16x16x32_bf16(a0, b0, acc[t][nt], 0, 0, 0);
            acc[t][nt] = __builtin_amdgcn_mfma_f32_16x16x32_bf16(a1, b1, acc[t][nt], 0, 0, 0);
        }
    }
    // direct bf16 store: state [d][f], ksum [f]
    {
        unsigned short* st = wskv + (size_t)(h * NCHUNK + c) * STATE_E;
        #pragma unroll
        for (int t = 0; t < 2; ++t) {
            int fb = (wave * 2 + t) * 16 + quad * 4;
            #pragma unroll
            for (int nt = 0; nt < 4; ++nt) {
                int d = nt * 16 + lrow;
                *(ushort4*)(st + d * 128 + fb) =
                    make_ushort4(f2bf(acc[t][nt][0]), f2bf(acc[t][nt][1]),
                                 f2bf(acc[t][nt][2]), f2bf(acc[t][nt][3]));
            }
            if (lrow == 0)
                *(ushort4*)(wsks + (size_t)(h * NCHUNK + c) * 128 + fb) =
                    make_ushort4(f2bf(acc[t][4][0]), f2bf(acc[t][4][1]),
                                 f2bf(acc[t][4][2]), f2bf(acc[t][4][3]));
        }
    }

    // ---- grid-wide barrier (all 256 blocks co-resident: 1 per CU) ----
    __syncthreads();                    // drains each thread's stores (vmcnt)
    if (tid == 0) {
        __threadfence();                // agent-scope release of state writes
        __hip_atomic_fetch_add(bar, 1u, __ATOMIC_ACQ_REL, __HIP_MEMORY_SCOPE_AGENT);
        while (__hip_atomic_load(bar, __ATOMIC_ACQUIRE, __HIP_MEMORY_SCOPE_AGENT)
               < (unsigned)NBLK)
            __builtin_amdgcn_s_sleep(8);
    }
    __syncthreads();

    // ---- phase B: accumulate exclusive prefix state into Bv / Bk ----
    {
        const unsigned short* base = wskv + (size_t)h * NCHUNK * STATE_E;
        #pragma unroll
        for (int i = 0; i < 4; ++i) {
            int idx = i * 256 + tid;
            int d = idx >> 4, f8 = (idx & 15) * 8;
            float s[8];
            #pragma unroll
            for (int x = 0; x < 8; ++x) s[x] = 0.f;
            for (int cp = 0; cp < c; ++cp) {
                uint4 u = *(const uint4*)(base + (size_t)cp * STATE_E + d * 128 + f8);
                s[0] += bflo(u.x); s[1] += bfhi(u.x);
                s[2] += bflo(u.y); s[3] += bfhi(u.y);
                s[4] += bflo(u.z); s[5] += bfhi(u.z);
                s[6] += bflo(u.w); s[7] += bfhi(u.w);
            }
            *(ushort4*)&Bv[d * SV + 64 + f8] =
                make_ushort4(f2bf(s[0]), f2bf(s[1]), f2bf(s[2]), f2bf(s[3]));
            *(ushort4*)&Bv[d * SV + 64 + f8 + 4] =
                make_ushort4(f2bf(s[4]), f2bf(s[5]), f2bf(s[6]), f2bf(s[7]));
        }
        if (tid < 16) {
            const unsigned short* kb = wsks + (size_t)h * NCHUNK * 128;
            float s[8];
            #pragma unroll
            for (int x = 0; x < 8; ++x) s[x] = 0.f;
            for (int cp = 0; cp < c; ++cp) {
                uint4 u = *(const uint4*)(kb + cp * 128 + tid * 8);
                s[0] += bflo(u.x); s[1] += bfhi(u.x);
                s[2] += bflo(u.y); s[3] += bfhi(u.y);
                s[4] += bflo(u.z); s[5] += bfhi(u.z);
                s[6] += bflo(u.w); s[7] += bfhi(u.w);
            }
            *(ushort4*)&Bk[64 * SB + tid * 8] =
                make_ushort4(f2bf(s[0]), f2bf(s[1]), f2bf(s[2]), f2bf(s[3]));
            *(ushort4*)&Bk[64 * SB + tid * 8 + 4] =
                make_ushort4(f2bf(s[4]), f2bf(s[5]), f2bf(s[6]), f2bf(s[7]));
        }
    }
    __syncthreads();

    // ---- GEMM1: scores + denominator ----
    const int l0 = wave * 16;
    const int arow = (l0 + lrow) * SA;
    short8 a1f[4];
    #pragma unroll
    for (int ks = 0; ks < 4; ++ks)
        a1f[ks] = *(const short8*)&Aq[arow + 64 + ks * 32 + quad * 8];
    floatx4 rs = {0.f, 0.f, 0.f, 0.f};
    #pragma unroll
    for (int nt = 0; nt < 5; ++nt) {
        floatx4 s = {0.f, 0.f, 0.f, 0.f};
        #pragma unroll
        for (int ks = 0; ks < 4; ++ks) {
            short8 bf = *(const short8*)&Bk[(nt * 16 + lrow) * SB + ks * 32 + quad * 8];
            s = __builtin_amdgcn_mfma_f32_16x16x32_bf16(a1f[ks], bf, s, 0, 0, 0);
        }
        if (nt < 4) {
            int j = nt * 16 + lrow;
            #pragma unroll
            for (int r = 0; r < 4; ++r) {
                int l = l0 + quad * 4 + r;
                float m = (j <= l) ? s[r] : 0.f;
                s[r] = m;
                Aq[l * SA + j] = f2bf(m);    // masked score -> A-layout for GEMM2
            }
        }
        rs += s;    // nt==4: col 64 = qf.ksum; cols 65..79 exact zeros
    }
    #pragma unroll
    for (int m = 1; m <= 8; m <<= 1) {
        rs[0] += __shfl_xor(rs[0], m);
        rs[1] += __shfl_xor(rs[1], m);
        rs[2] += __shfl_xor(rs[2], m);
        rs[3] += __shfl_xor(rs[3], m);
    }
    float inv[4];
    #pragma unroll
    for (int r = 0; r < 4; ++r) inv[r] = 1.0f / fmaxf(rs[r], EPSV);

    __syncthreads();

    // ---- GEMM2: O = [scores | qf] * [V ; S] ----
    short8 s0 = *(const short8*)&Aq[arow + quad * 8];
    short8 s1 = *(const short8*)&Aq[arow + 32 + quad * 8];
    #pragma unroll
    for (int nt = 0; nt < 4; ++nt) {
        const int brow = (nt * 16 + lrow) * SV;
        floatx4 a2 = {0.f, 0.f, 0.f, 0.f};
        a2 = __builtin_amdgcn_mfma_f32_16x16x32_bf16(
                 s0, *(const short8*)&Bv[brow + quad * 8], a2, 0, 0, 0);
        a2 = __builtin_amdgcn_mfma_f32_16x16x32_bf16(
                 s1, *(const short8*)&Bv[brow + 32 + quad * 8], a2, 0, 0, 0);
        #pragma unroll
        for (int ks = 2; ks < 6; ++ks) {
            short8 bf = *(const short8*)&Bv[brow + ks * 32 + quad * 8];
            a2 = __builtin_amdgcn_mfma_f32_16x16x32_bf16(a1f[ks - 2], bf, a2, 0, 0, 0);
        }
        #pragma unroll
        for (int r = 0; r < 4; ++r) {
            int l = l0 + quad * 4 + r;
            out[gbase + (size_t)l * Dd + nt * 16 + lrow] = a2[r] * inv[r];
        }
    }
}

extern "C" void kernel_launch(void* const* d_in, const int* in_sizes, int n_in,
                              void* d_out, int out_size, void* d_ws, size_t ws_size,
                              hipStream_t stream) {
    const float* q = (const float*)d_in[0];
    const float* k = (const float*)d_in[1];
    const float* v = (const float*)d_in[2];
    float* out = (float*)d_out;
    unsigned int* bar = (unsigned int*)d_ws;                       // 64 B
    unsigned short* wskv = (unsigned short*)d_ws + 128;            // 4 MB states
    unsigned short* wsks = wskv + (size_t)NBLK * STATE_E;          // 64 KB ksums
    hipMemsetAsync(bar, 0, 64, stream);                            // capture-legal
    cf_onekernel<<<dim3(NCHUNK, Hh), 256, 0, stream>>>(q, k, v, out, bar, wskv, wsks);
}

// Round 6
// 88.059 us; speedup vs baseline: 1.3187x; 1.3187x over previous
//
#include <hip/hip_runtime.h>

namespace {
constexpr int Hh = 16;
constexpr int Ll = 1024;
constexpr int Dd = 64;
constexpr int Cc = 64;                   // chunk length
constexpr int NCHUNK = Ll / Cc;          // 16
constexpr int NBLK = Hh * NCHUNK;        // 256
constexpr float PI_HALF = 1.5707963267948966f;
constexpr float EPSV = 1e-6f;
constexpr int S1 = 72;                   // k1 operand stride (shorts)
constexpr int SA = 200;                  // Aq stride
constexpr int SB = 136;                  // Bk stride
constexpr int SV = 200;                  // Bv stride
constexpr int STATE_E = 128 * 64;        // bf16 elems per chunk state [d][f]
}

typedef __attribute__((ext_vector_type(8))) short short8;
typedef __attribute__((ext_vector_type(4))) float floatx4;

__device__ __forceinline__ unsigned short f2bf(float x) {
    unsigned int u = __float_as_uint(x);
    unsigned int r = u + 0x7fffu + ((u >> 16) & 1u);
    return (unsigned short)(r >> 16);
}
__device__ __forceinline__ float bfhi(unsigned int u) {
    return __uint_as_float(u & 0xffff0000u);
}
__device__ __forceinline__ float bflo(unsigned int u) {
    return __uint_as_float(u << 16);
}

// XOR swizzle (validated rounds 4/5): spreads strided transpose writes across
// banks while keeping MFMA fragment reads b128.
__device__ __forceinline__ int sw1(int row, int j) {
    return (j & 7) | ((((j >> 3) ^ (row >> 3)) & 7) << 3);
}

// ---------------------------------------------------------------------------
// Kernel 1: per (h,c) chunk state via MFMA (round-5 phase A, verbatim):
//   state[d][f] = sum_j kf[j][f] * v[j][d],  ksum[f] = sum_j kf[j][f]
__global__ __launch_bounds__(256)
void cf_sums(const float* __restrict__ kin, const float* __restrict__ vin,
             unsigned short* __restrict__ wskv, unsigned short* __restrict__ wsks) {
    const int c = blockIdx.x, h = blockIdx.y;
    const int tid = threadIdx.x;
    __shared__ unsigned short Ak[128 * S1];   // kf^T [f][j] (swizzled j)
    __shared__ unsigned short Bv1[80 * S1];   // [V|1]^T [n][j] (swizzled j)

    const int wave = tid >> 6, lane = tid & 63;
    const int lrow = lane & 15, quad = lane >> 4;

    const size_t gbase = ((size_t)h * Ll + (size_t)c * Cc) * Dd;
    const float4* k4 = (const float4*)(kin + gbase);
    const float4* v4 = (const float4*)(vin + gbase);
    #pragma unroll
    for (int i = 0; i < 4; ++i) {
        int e4 = i * 256 + tid;
        int j = e4 >> 4, d4 = (e4 & 15) * 4;
        float th = PI_HALF * (float)(c * Cc + j + 1) * (1.0f / (float)Ll);
        float sj, cj;
        __sincosf(th, &sj, &cj);
        float4 kx = k4[e4];
        float k0 = fmaxf(kx.x, 0.f), k1 = fmaxf(kx.y, 0.f);
        float k2 = fmaxf(kx.z, 0.f), k3 = fmaxf(kx.w, 0.f);
        int col = sw1(d4, j);
        Ak[(d4 + 0) * S1 + col] = f2bf(k0 * sj);
        Ak[(d4 + 1) * S1 + col] = f2bf(k1 * sj);
        Ak[(d4 + 2) * S1 + col] = f2bf(k2 * sj);
        Ak[(d4 + 3) * S1 + col] = f2bf(k3 * sj);
        Ak[(64 + d4 + 0) * S1 + col] = f2bf(k0 * cj);
        Ak[(64 + d4 + 1) * S1 + col] = f2bf(k1 * cj);
        Ak[(64 + d4 + 2) * S1 + col] = f2bf(k2 * cj);
        Ak[(64 + d4 + 3) * S1 + col] = f2bf(k3 * cj);
        float4 vx = v4[e4];
        Bv1[(d4 + 0) * S1 + col] = f2bf(vx.x);
        Bv1[(d4 + 1) * S1 + col] = f2bf(vx.y);
        Bv1[(d4 + 2) * S1 + col] = f2bf(vx.z);
        Bv1[(d4 + 3) * S1 + col] = f2bf(vx.w);
    }
    // row 64 = ones (row-64 swizzle key is 0), rows 65..79 = 0
    if (tid < 64) Bv1[64 * S1 + tid] = 0x3F80;
    if (tid >= 64 && tid < S1) Bv1[64 * S1 + tid] = 0;
    #pragma unroll
    for (int i = 0; i < 3; ++i) {
        int z = i * 256 + tid;
        if (z < (15 * S1) / 2) ((unsigned int*)Bv1)[(65 * S1) / 2 + z] = 0u;
    }
    __syncthreads();

    floatx4 acc[2][5];
    #pragma unroll
    for (int t = 0; t < 2; ++t)
        #pragma unroll
        for (int nt = 0; nt < 5; ++nt)
            acc[t][nt] = (floatx4){0.f, 0.f, 0.f, 0.f};
    #pragma unroll
    for (int t = 0; t < 2; ++t) {
        int fr = (wave * 2 + t) * 16 + lrow;
        int keyA = (fr >> 3) & 7;
        short8 a0 = *(const short8*)&Ak[fr * S1 + ((quad ^ keyA) << 3)];
        short8 a1 = *(const short8*)&Ak[fr * S1 + (((4 + quad) ^ keyA) << 3)];
        #pragma unroll
        for (int nt = 0; nt < 5; ++nt) {
            int nr = nt * 16 + lrow;
            int keyB = (nr >> 3) & 7;
            short8 b0 = *(const short8*)&Bv1[nr * S1 + ((quad ^ keyB) << 3)];
            short8 b1 = *(const short8*)&Bv1[nr * S1 + (((4 + quad) ^ keyB) << 3)];
            acc[t][nt] = __builtin_amdgcn_mfma_f32_16x16x32_bf16(a0, b0, acc[t][nt], 0, 0, 0);
            acc[t][nt] = __builtin_amdgcn_mfma_f32_16x16x32_bf16(a1, b1, acc[t][nt], 0, 0, 0);
        }
    }
    unsigned short* st = wskv + (size_t)(h * NCHUNK + c) * STATE_E;
    #pragma unroll
    for (int t = 0; t < 2; ++t) {
        int fb = (wave * 2 + t) * 16 + quad * 4;
        #pragma unroll
        for (int nt = 0; nt < 4; ++nt) {
            int d = nt * 16 + lrow;
            *(ushort4*)(st + d * 128 + fb) =
                make_ushort4(f2bf(acc[t][nt][0]), f2bf(acc[t][nt][1]),
                             f2bf(acc[t][nt][2]), f2bf(acc[t][nt][3]));
        }
        if (lrow == 0)
            *(ushort4*)(wsks + (size_t)(h * NCHUNK + c) * 128 + fb) =
                make_ushort4(f2bf(acc[t][4][0]), f2bf(acc[t][4][1]),
                             f2bf(acc[t][4][2]), f2bf(acc[t][4][3]));
    }
}

// ---------------------------------------------------------------------------
// Kernel 2: per (h,c) output. Accumulates exclusive prefix state directly
// from ws (fp32), then GEMM1 (scores + denominator) + GEMM2 (round 3/5).
__global__ __launch_bounds__(256)
void cf_out(const float* __restrict__ qin, const float* __restrict__ kin,
            const float* __restrict__ vin,
            const unsigned short* __restrict__ wskv,
            const unsigned short* __restrict__ wsks,
            float* __restrict__ out) {
    const int c = blockIdx.x, h = blockIdx.y;
    const int tid = threadIdx.x;
    __shared__ unsigned short Aq[64 * SA];    // [l][0..63 scores | 64..191 qf]
    __shared__ unsigned short Bk[80 * SB];    // [n=j][k=f]; row 64 = ksum; 65..79=0
    __shared__ unsigned short Bv[64 * SV];    // [n=d][0..63 V^T | 64..191 S]

    const int wave = tid >> 6, lane = tid & 63;
    const int lrow = lane & 15, quad = lane >> 4;

    const size_t gbase = ((size_t)h * Ll + (size_t)c * Cc) * Dd;
    const float4* q4 = (const float4*)(qin + gbase);
    const float4* k4 = (const float4*)(kin + gbase);
    const float4* v4 = (const float4*)(vin + gbase);

    // ---- stage own chunk ----
    #pragma unroll
    for (int i = 0; i < 4; ++i) {
        int e4 = i * 256 + tid;
        int j = e4 >> 4, d4 = (e4 & 15) * 4;
        float th = PI_HALF * (float)(c * Cc + j + 1) * (1.0f / (float)Ll);
        float sj, cj;
        __sincosf(th, &sj, &cj);
        float4 qv = q4[e4];
        float q0 = fmaxf(qv.x, 0.f), q1 = fmaxf(qv.y, 0.f);
        float q2 = fmaxf(qv.z, 0.f), q3 = fmaxf(qv.w, 0.f);
        *(ushort4*)&Aq[j * SA + 64 + d4] =
            make_ushort4(f2bf(q0 * sj), f2bf(q1 * sj), f2bf(q2 * sj), f2bf(q3 * sj));
        *(ushort4*)&Aq[j * SA + 128 + d4] =
            make_ushort4(f2bf(q0 * cj), f2bf(q1 * cj), f2bf(q2 * cj), f2bf(q3 * cj));
        float4 kx = k4[e4];
        float k0 = fmaxf(kx.x, 0.f), k1 = fmaxf(kx.y, 0.f);
        float k2 = fmaxf(kx.z, 0.f), k3 = fmaxf(kx.w, 0.f);
        *(ushort4*)&Bk[j * SB + d4] =
            make_ushort4(f2bf(k0 * sj), f2bf(k1 * sj), f2bf(k2 * sj), f2bf(k3 * sj));
        *(ushort4*)&Bk[j * SB + 64 + d4] =
            make_ushort4(f2bf(k0 * cj), f2bf(k1 * cj), f2bf(k2 * cj), f2bf(k3 * cj));
        float4 vx = v4[e4];
        Bv[(d4 + 0) * SV + j] = f2bf(vx.x);
        Bv[(d4 + 1) * SV + j] = f2bf(vx.y);
        Bv[(d4 + 2) * SV + j] = f2bf(vx.z);
        Bv[(d4 + 3) * SV + j] = f2bf(vx.w);
    }
    // zero Bk rows 65..79
    #pragma unroll
    for (int i = 0; i < 4; ++i) {
        int z = i * 256 + tid;
        if (z < (15 * SB) / 2) ((unsigned int*)Bk)[(65 * SB) / 2 + z] = 0u;
    }

    // ---- exclusive prefix state: fp32 sum of cp<c chunk states ----
    {
        const unsigned short* base = wskv + (size_t)h * NCHUNK * STATE_E;
        #pragma unroll
        for (int i = 0; i < 4; ++i) {
            int idx = i * 256 + tid;
            int d = idx >> 4, f8 = (idx & 15) * 8;
            float s[8];
            #pragma unroll
            for (int x = 0; x < 8; ++x) s[x] = 0.f;
            for (int cp = 0; cp < c; ++cp) {
                uint4 u = *(const uint4*)(base + (size_t)cp * STATE_E + d * 128 + f8);
                s[0] += bflo(u.x); s[1] += bfhi(u.x);
                s[2] += bflo(u.y); s[3] += bfhi(u.y);
                s[4] += bflo(u.z); s[5] += bfhi(u.z);
                s[6] += bflo(u.w); s[7] += bfhi(u.w);
            }
            *(ushort4*)&Bv[d * SV + 64 + f8] =
                make_ushort4(f2bf(s[0]), f2bf(s[1]), f2bf(s[2]), f2bf(s[3]));
            *(ushort4*)&Bv[d * SV + 64 + f8 + 4] =
                make_ushort4(f2bf(s[4]), f2bf(s[5]), f2bf(s[6]), f2bf(s[7]));
        }
        if (tid < 16) {
            const unsigned short* kb = wsks + (size_t)h * NCHUNK * 128;
            float s[8];
            #pragma unroll
            for (int x = 0; x < 8; ++x) s[x] = 0.f;
            for (int cp = 0; cp < c; ++cp) {
                uint4 u = *(const uint4*)(kb + cp * 128 + tid * 8);
                s[0] += bflo(u.x); s[1] += bfhi(u.x);
                s[2] += bflo(u.y); s[3] += bfhi(u.y);
                s[4] += bflo(u.z); s[5] += bfhi(u.z);
                s[6] += bflo(u.w); s[7] += bfhi(u.w);
            }
            *(ushort4*)&Bk[64 * SB + tid * 8] =
                make_ushort4(f2bf(s[0]), f2bf(s[1]), f2bf(s[2]), f2bf(s[3]));
            *(ushort4*)&Bk[64 * SB + tid * 8 + 4] =
                make_ushort4(f2bf(s[4]), f2bf(s[5]), f2bf(s[6]), f2bf(s[7]));
        }
    }
    __syncthreads();

    // ---- GEMM1: scores + denominator ----
    const int l0 = wave * 16;
    const int arow = (l0 + lrow) * SA;
    short8 a1f[4];
    #pragma unroll
    for (int ks = 0; ks < 4; ++ks)
        a1f[ks] = *(const short8*)&Aq[arow + 64 + ks * 32 + quad * 8];
    floatx4 rs = {0.f, 0.f, 0.f, 0.f};
    #pragma unroll
    for (int nt = 0; nt < 5; ++nt) {
        floatx4 s = {0.f, 0.f, 0.f, 0.f};
        #pragma unroll
        for (int ks = 0; ks < 4; ++ks) {
            short8 bf = *(const short8*)&Bk[(nt * 16 + lrow) * SB + ks * 32 + quad * 8];
            s = __builtin_amdgcn_mfma_f32_16x16x32_bf16(a1f[ks], bf, s, 0, 0, 0);
        }
        if (nt < 4) {
            int j = nt * 16 + lrow;
            #pragma unroll
            for (int r = 0; r < 4; ++r) {
                int l = l0 + quad * 4 + r;
                float m = (j <= l) ? s[r] : 0.f;
                s[r] = m;
                Aq[l * SA + j] = f2bf(m);    // masked score -> A-layout for GEMM2
            }
        }
        rs += s;    // nt==4: col 64 = qf.ksum; cols 65..79 exact zeros
    }
    #pragma unroll
    for (int m = 1; m <= 8; m <<= 1) {
        rs[0] += __shfl_xor(rs[0], m);
        rs[1] += __shfl_xor(rs[1], m);
        rs[2] += __shfl_xor(rs[2], m);
        rs[3] += __shfl_xor(rs[3], m);
    }
    float inv[4];
    #pragma unroll
    for (int r = 0; r < 4; ++r) inv[r] = 1.0f / fmaxf(rs[r], EPSV);

    __syncthreads();

    // ---- GEMM2: O = [scores | qf] * [V ; S] ----
    short8 s0 = *(const short8*)&Aq[arow + quad * 8];
    short8 s1 = *(const short8*)&Aq[arow + 32 + quad * 8];
    #pragma unroll
    for (int nt = 0; nt < 4; ++nt) {
        const int brow = (nt * 16 + lrow) * SV;
        floatx4 a2 = {0.f, 0.f, 0.f, 0.f};
        a2 = __builtin_amdgcn_mfma_f32_16x16x32_bf16(
                 s0, *(const short8*)&Bv[brow + quad * 8], a2, 0, 0, 0);
        a2 = __builtin_amdgcn_mfma_f32_16x16x32_bf16(
                 s1, *(const short8*)&Bv[brow + 32 + quad * 8], a2, 0, 0, 0);
        #pragma unroll
        for (int ks = 2; ks < 6; ++ks) {
            short8 bf = *(const short8*)&Bv[brow + ks * 32 + quad * 8];
            a2 = __builtin_amdgcn_mfma_f32_16x16x32_bf16(a1f[ks - 2], bf, a2, 0, 0, 0);
        }
        #pragma unroll
        for (int r = 0; r < 4; ++r) {
            int l = l0 + quad * 4 + r;
            out[gbase + (size_t)l * Dd + nt * 16 + lrow] = a2[r] * inv[r];
        }
    }
}

extern "C" void kernel_launch(void* const* d_in, const int* in_sizes, int n_in,
                              void* d_out, int out_size, void* d_ws, size_t ws_size,
                              hipStream_t stream) {
    const float* q = (const float*)d_in[0];
    const float* k = (const float*)d_in[1];
    const float* v = (const float*)d_in[2];
    float* out = (float*)d_out;
    unsigned short* wskv = (unsigned short*)d_ws;                 // 4 MB states
    unsigned short* wsks = wskv + (size_t)NBLK * STATE_E;         // 64 KB ksums
    dim3 grid(NCHUNK, Hh);
    cf_sums<<<grid, 256, 0, stream>>>(k, v, wskv, wsks);
    cf_out<<<grid, 256, 0, stream>>>(q, k, v, wskv, wsks, out);
}

// Round 7
// 81.828 us; speedup vs baseline: 1.4191x; 1.0761x over previous
//
#include <hip/hip_runtime.h>

namespace {
constexpr int Hh = 16;
constexpr int Ll = 1024;
constexpr int Dd = 64;
constexpr int Cc = 64;                   // chunk length
constexpr int NCHUNK = Ll / Cc;          // 16
constexpr int NBLK = Hh * NCHUNK;        // 256
constexpr float PI_HALF = 1.5707963267948966f;
constexpr float EPSV = 1e-6f;
constexpr int S1 = 72;                   // k1 operand stride (shorts)
constexpr int SA = 200;                  // Aq stride
constexpr int SB = 136;                  // Bk stride
constexpr int SV = 200;                  // Bv stride
constexpr int STATE_E = 128 * 64;        // bf16 elems per chunk state [d][f]
}

typedef __attribute__((ext_vector_type(8))) short short8;
typedef __attribute__((ext_vector_type(4))) float floatx4;

__device__ __forceinline__ unsigned short f2bf(float x) {
    unsigned int u = __float_as_uint(x);
    unsigned int r = u + 0x7fffu + ((u >> 16) & 1u);
    return (unsigned short)(r >> 16);
}
__device__ __forceinline__ float bfhi(unsigned int u) {
    return __uint_as_float(u & 0xffff0000u);
}
__device__ __forceinline__ float bflo(unsigned int u) {
    return __uint_as_float(u << 16);
}

// XOR swizzle (validated rounds 4-6): spreads strided transpose writes across
// banks while keeping MFMA fragment reads b128.
__device__ __forceinline__ int sw1(int row, int j) {
    return (j & 7) | ((((j >> 3) ^ (row >> 3)) & 7) << 3);
}

// ---------------------------------------------------------------------------
// Kernel 1 (validated r5/r6, verbatim): per (h,c) chunk state via MFMA:
//   state[d][f] = sum_j kf[j][f] * v[j][d],  ksum[f] = sum_j kf[j][f]
__global__ __launch_bounds__(256)
void cf_sums(const float* __restrict__ kin, const float* __restrict__ vin,
             unsigned short* __restrict__ wskv, unsigned short* __restrict__ wsks) {
    const int c = blockIdx.x, h = blockIdx.y;
    const int tid = threadIdx.x;
    __shared__ unsigned short Ak[128 * S1];   // kf^T [f][j] (swizzled j)
    __shared__ unsigned short Bv1[80 * S1];   // [V|1]^T [n][j] (swizzled j)

    const int wave = tid >> 6, lane = tid & 63;
    const int lrow = lane & 15, quad = lane >> 4;

    const size_t gbase = ((size_t)h * Ll + (size_t)c * Cc) * Dd;
    const float4* k4 = (const float4*)(kin + gbase);
    const float4* v4 = (const float4*)(vin + gbase);
    #pragma unroll
    for (int i = 0; i < 4; ++i) {
        int e4 = i * 256 + tid;
        int j = e4 >> 4, d4 = (e4 & 15) * 4;
        float th = PI_HALF * (float)(c * Cc + j + 1) * (1.0f / (float)Ll);
        float sj, cj;
        __sincosf(th, &sj, &cj);
        float4 kx = k4[e4];
        float k0 = fmaxf(kx.x, 0.f), k1 = fmaxf(kx.y, 0.f);
        float k2 = fmaxf(kx.z, 0.f), k3 = fmaxf(kx.w, 0.f);
        int col = sw1(d4, j);
        Ak[(d4 + 0) * S1 + col] = f2bf(k0 * sj);
        Ak[(d4 + 1) * S1 + col] = f2bf(k1 * sj);
        Ak[(d4 + 2) * S1 + col] = f2bf(k2 * sj);
        Ak[(d4 + 3) * S1 + col] = f2bf(k3 * sj);
        Ak[(64 + d4 + 0) * S1 + col] = f2bf(k0 * cj);
        Ak[(64 + d4 + 1) * S1 + col] = f2bf(k1 * cj);
        Ak[(64 + d4 + 2) * S1 + col] = f2bf(k2 * cj);
        Ak[(64 + d4 + 3) * S1 + col] = f2bf(k3 * cj);
        float4 vx = v4[e4];
        Bv1[(d4 + 0) * S1 + col] = f2bf(vx.x);
        Bv1[(d4 + 1) * S1 + col] = f2bf(vx.y);
        Bv1[(d4 + 2) * S1 + col] = f2bf(vx.z);
        Bv1[(d4 + 3) * S1 + col] = f2bf(vx.w);
    }
    // row 64 = ones (row-64 swizzle key is 0), rows 65..79 = 0
    if (tid < 64) Bv1[64 * S1 + tid] = 0x3F80;
    if (tid >= 64 && tid < S1) Bv1[64 * S1 + tid] = 0;
    #pragma unroll
    for (int i = 0; i < 3; ++i) {
        int z = i * 256 + tid;
        if (z < (15 * S1) / 2) ((unsigned int*)Bv1)[(65 * S1) / 2 + z] = 0u;
    }
    __syncthreads();

    floatx4 acc[2][5];
    #pragma unroll
    for (int t = 0; t < 2; ++t)
        #pragma unroll
        for (int nt = 0; nt < 5; ++nt)
            acc[t][nt] = (floatx4){0.f, 0.f, 0.f, 0.f};
    #pragma unroll
    for (int t = 0; t < 2; ++t) {
        int fr = (wave * 2 + t) * 16 + lrow;
        int keyA = (fr >> 3) & 7;
        short8 a0 = *(const short8*)&Ak[fr * S1 + ((quad ^ keyA) << 3)];
        short8 a1 = *(const short8*)&Ak[fr * S1 + (((4 + quad) ^ keyA) << 3)];
        #pragma unroll
        for (int nt = 0; nt < 5; ++nt) {
            int nr = nt * 16 + lrow;
            int keyB = (nr >> 3) & 7;
            short8 b0 = *(const short8*)&Bv1[nr * S1 + ((quad ^ keyB) << 3)];
            short8 b1 = *(const short8*)&Bv1[nr * S1 + (((4 + quad) ^ keyB) << 3)];
            acc[t][nt] = __builtin_amdgcn_mfma_f32_16x16x32_bf16(a0, b0, acc[t][nt], 0, 0, 0);
            acc[t][nt] = __builtin_amdgcn_mfma_f32_16x16x32_bf16(a1, b1, acc[t][nt], 0, 0, 0);
        }
    }
    unsigned short* st = wskv + (size_t)(h * NCHUNK + c) * STATE_E;
    #pragma unroll
    for (int t = 0; t < 2; ++t) {
        int fb = (wave * 2 + t) * 16 + quad * 4;
        #pragma unroll
        for (int nt = 0; nt < 4; ++nt) {
            int d = nt * 16 + lrow;
            *(ushort4*)(st + d * 128 + fb) =
                make_ushort4(f2bf(acc[t][nt][0]), f2bf(acc[t][nt][1]),
                             f2bf(acc[t][nt][2]), f2bf(acc[t][nt][3]));
        }
        if (lrow == 0)
            *(ushort4*)(wsks + (size_t)(h * NCHUNK + c) * 128 + fb) =
                make_ushort4(f2bf(acc[t][4][0]), f2bf(acc[t][4][1]),
                             f2bf(acc[t][4][2]), f2bf(acc[t][4][3]));
    }
}

// ---------------------------------------------------------------------------
// Kernel 2: per (h,c) output. Prefix-state accumulation restructured for
// memory-level parallelism: 4 slices per cp iteration + 1-deep prefetch
// (8 uint4 loads in flight), overlapped with the sincos staging conversion.
__global__ __launch_bounds__(256)
void cf_out(const float* __restrict__ qin, const float* __restrict__ kin,
            const float* __restrict__ vin,
            const unsigned short* __restrict__ wskv,
            const unsigned short* __restrict__ wsks,
            float* __restrict__ out) {
    const int c = blockIdx.x, h = blockIdx.y;
    const int tid = threadIdx.x;
    __shared__ unsigned short Aq[64 * SA];    // [l][0..63 scores | 64..191 qf]
    __shared__ unsigned short Bk[80 * SB];    // [n=j][k=f]; row 64 = ksum; 65..79=0
    __shared__ unsigned short Bv[64 * SV];    // [n=d][0..63 V^T | 64..191 S]

    const int wave = tid >> 6, lane = tid & 63;
    const int lrow = lane & 15, quad = lane >> 4;

    const size_t gbase = ((size_t)h * Ll + (size_t)c * Cc) * Dd;
    const float4* q4 = (const float4*)(qin + gbase);
    const float4* k4 = (const float4*)(kin + gbase);
    const float4* v4 = (const float4*)(vin + gbase);

    // ---- issue own-chunk loads into registers first ----
    float4 oq[4], ok[4], ov[4];
    #pragma unroll
    for (int i = 0; i < 4; ++i) {
        oq[i] = q4[i * 256 + tid];
        ok[i] = k4[i * 256 + tid];
        ov[i] = v4[i * 256 + tid];
    }

    // ---- prefix-state accumulation with MLP (4 slices + prefetch) ----
    float sacc[4][8];
    #pragma unroll
    for (int i = 0; i < 4; ++i)
        #pragma unroll
        for (int x = 0; x < 8; ++x) sacc[i][x] = 0.f;
    int off[4];
    #pragma unroll
    for (int i = 0; i < 4; ++i) {
        int idx = i * 256 + tid;
        off[i] = (idx >> 4) * 128 + (idx & 15) * 8;   // d*128 + f8
    }
    const unsigned short* sbase = wskv + (size_t)h * NCHUNK * STATE_E;
    if (c > 0) {
        uint4 cur[4];
        #pragma unroll
        for (int i = 0; i < 4; ++i)
            cur[i] = *(const uint4*)(sbase + off[i]);
        for (int cp = 0; cp < c; ++cp) {
            uint4 nxt[4];
            if (cp + 1 < c) {
                const unsigned short* p = sbase + (size_t)(cp + 1) * STATE_E;
                #pragma unroll
                for (int i = 0; i < 4; ++i)
                    nxt[i] = *(const uint4*)(p + off[i]);
            }
            #pragma unroll
            for (int i = 0; i < 4; ++i) {
                sacc[i][0] += bflo(cur[i].x); sacc[i][1] += bfhi(cur[i].x);
                sacc[i][2] += bflo(cur[i].y); sacc[i][3] += bfhi(cur[i].y);
                sacc[i][4] += bflo(cur[i].z); sacc[i][5] += bfhi(cur[i].z);
                sacc[i][6] += bflo(cur[i].w); sacc[i][7] += bfhi(cur[i].w);
            }
            if (cp + 1 < c) {
                #pragma unroll
                for (int i = 0; i < 4; ++i) cur[i] = nxt[i];
            }
        }
    }
    // ksum prefix (one wave's lanes 0..15; hidden by other waves)
    float ksacc[8];
    #pragma unroll
    for (int x = 0; x < 8; ++x) ksacc[x] = 0.f;
    if (tid < 16) {
        const unsigned short* kb = wsks + (size_t)h * NCHUNK * 128;
        for (int cp = 0; cp < c; ++cp) {
            uint4 u = *(const uint4*)(kb + cp * 128 + tid * 8);
            ksacc[0] += bflo(u.x); ksacc[1] += bfhi(u.x);
            ksacc[2] += bflo(u.y); ksacc[3] += bfhi(u.y);
            ksacc[4] += bflo(u.z); ksacc[5] += bfhi(u.z);
            ksacc[6] += bflo(u.w); ksacc[7] += bfhi(u.w);
        }
    }

    // ---- staging conversion (registers already loaded) ----
    #pragma unroll
    for (int i = 0; i < 4; ++i) {
        int e4 = i * 256 + tid;
        int j = e4 >> 4, d4 = (e4 & 15) * 4;
        float th = PI_HALF * (float)(c * Cc + j + 1) * (1.0f / (float)Ll);
        float sj, cj;
        __sincosf(th, &sj, &cj);
        float q0 = fmaxf(oq[i].x, 0.f), q1 = fmaxf(oq[i].y, 0.f);
        float q2 = fmaxf(oq[i].z, 0.f), q3 = fmaxf(oq[i].w, 0.f);
        *(ushort4*)&Aq[j * SA + 64 + d4] =
            make_ushort4(f2bf(q0 * sj), f2bf(q1 * sj), f2bf(q2 * sj), f2bf(q3 * sj));
        *(ushort4*)&Aq[j * SA + 128 + d4] =
            make_ushort4(f2bf(q0 * cj), f2bf(q1 * cj), f2bf(q2 * cj), f2bf(q3 * cj));
        float k0 = fmaxf(ok[i].x, 0.f), k1 = fmaxf(ok[i].y, 0.f);
        float k2 = fmaxf(ok[i].z, 0.f), k3 = fmaxf(ok[i].w, 0.f);
        *(ushort4*)&Bk[j * SB + d4] =
            make_ushort4(f2bf(k0 * sj), f2bf(k1 * sj), f2bf(k2 * sj), f2bf(k3 * sj));
        *(ushort4*)&Bk[j * SB + 64 + d4] =
            make_ushort4(f2bf(k0 * cj), f2bf(k1 * cj), f2bf(k2 * cj), f2bf(k3 * cj));
        Bv[(d4 + 0) * SV + j] = f2bf(ov[i].x);
        Bv[(d4 + 1) * SV + j] = f2bf(ov[i].y);
        Bv[(d4 + 2) * SV + j] = f2bf(ov[i].z);
        Bv[(d4 + 3) * SV + j] = f2bf(ov[i].w);
    }
    // zero Bk rows 65..79
    #pragma unroll
    for (int i = 0; i < 4; ++i) {
        int z = i * 256 + tid;
        if (z < (15 * SB) / 2) ((unsigned int*)Bk)[(65 * SB) / 2 + z] = 0u;
    }
    // write prefix state into Bv cols 64.. and Bk row 64
    #pragma unroll
    for (int i = 0; i < 4; ++i) {
        int idx = i * 256 + tid;
        int d = idx >> 4, f8 = (idx & 15) * 8;
        *(ushort4*)&Bv[d * SV + 64 + f8] =
            make_ushort4(f2bf(sacc[i][0]), f2bf(sacc[i][1]),
                         f2bf(sacc[i][2]), f2bf(sacc[i][3]));
        *(ushort4*)&Bv[d * SV + 64 + f8 + 4] =
            make_ushort4(f2bf(sacc[i][4]), f2bf(sacc[i][5]),
                         f2bf(sacc[i][6]), f2bf(sacc[i][7]));
    }
    if (tid < 16) {
        *(ushort4*)&Bk[64 * SB + tid * 8] =
            make_ushort4(f2bf(ksacc[0]), f2bf(ksacc[1]), f2bf(ksacc[2]), f2bf(ksacc[3]));
        *(ushort4*)&Bk[64 * SB + tid * 8 + 4] =
            make_ushort4(f2bf(ksacc[4]), f2bf(ksacc[5]), f2bf(ksacc[6]), f2bf(ksacc[7]));
    }
    __syncthreads();

    // ---- GEMM1: scores + denominator (validated) ----
    const int l0 = wave * 16;
    const int arow = (l0 + lrow) * SA;
    short8 a1f[4];
    #pragma unroll
    for (int ks = 0; ks < 4; ++ks)
        a1f[ks] = *(const short8*)&Aq[arow + 64 + ks * 32 + quad * 8];
    floatx4 rs = {0.f, 0.f, 0.f, 0.f};
    #pragma unroll
    for (int nt = 0; nt < 5; ++nt) {
        floatx4 s = {0.f, 0.f, 0.f, 0.f};
        #pragma unroll
        for (int ks = 0; ks < 4; ++ks) {
            short8 bf = *(const short8*)&Bk[(nt * 16 + lrow) * SB + ks * 32 + quad * 8];
            s = __builtin_amdgcn_mfma_f32_16x16x32_bf16(a1f[ks], bf, s, 0, 0, 0);
        }
        if (nt < 4) {
            int j = nt * 16 + lrow;
            #pragma unroll
            for (int r = 0; r < 4; ++r) {
                int l = l0 + quad * 4 + r;
                float m = (j <= l) ? s[r] : 0.f;
                s[r] = m;
                Aq[l * SA + j] = f2bf(m);    // masked score -> A-layout for GEMM2
            }
        }
        rs += s;    // nt==4: col 64 = qf.ksum; cols 65..79 exact zeros
    }
    #pragma unroll
    for (int m = 1; m <= 8; m <<= 1) {
        rs[0] += __shfl_xor(rs[0], m);
        rs[1] += __shfl_xor(rs[1], m);
        rs[2] += __shfl_xor(rs[2], m);
        rs[3] += __shfl_xor(rs[3], m);
    }
    float inv[4];
    #pragma unroll
    for (int r = 0; r < 4; ++r) inv[r] = 1.0f / fmaxf(rs[r], EPSV);

    __syncthreads();

    // ---- GEMM2: O = [scores | qf] * [V ; S] (validated) ----
    short8 s0 = *(const short8*)&Aq[arow + quad * 8];
    short8 s1 = *(const short8*)&Aq[arow + 32 + quad * 8];
    #pragma unroll
    for (int nt = 0; nt < 4; ++nt) {
        const int brow = (nt * 16 + lrow) * SV;
        floatx4 a2 = {0.f, 0.f, 0.f, 0.f};
        a2 = __builtin_amdgcn_mfma_f32_16x16x32_bf16(
                 s0, *(const short8*)&Bv[brow + quad * 8], a2, 0, 0, 0);
        a2 = __builtin_amdgcn_mfma_f32_16x16x32_bf16(
                 s1, *(const short8*)&Bv[brow + 32 + quad * 8], a2, 0, 0, 0);
        #pragma unroll
        for (int ks = 2; ks < 6; ++ks) {
            short8 bf = *(const short8*)&Bv[brow + ks * 32 + quad * 8];
            a2 = __builtin_amdgcn_mfma_f32_16x16x32_bf16(a1f[ks - 2], bf, a2, 0, 0, 0);
        }
        #pragma unroll
        for (int r = 0; r < 4; ++r) {
            int l = l0 + quad * 4 + r;
            out[gbase + (size_t)l * Dd + nt * 16 + lrow] = a2[r] * inv[r];
        }
    }
}

extern "C" void kernel_launch(void* const* d_in, const int* in_sizes, int n_in,
                              void* d_out, int out_size, void* d_ws, size_t ws_size,
                              hipStream_t stream) {
    const float* q = (const float*)d_in[0];
    const float* k = (const float*)d_in[1];
    const float* v = (const float*)d_in[2];
    float* out = (float*)d_out;
    unsigned short* wskv = (unsigned short*)d_ws;                 // 4 MB states
    unsigned short* wsks = wskv + (size_t)NBLK * STATE_E;         // 64 KB ksums
    dim3 grid(NCHUNK, Hh);
    cf_sums<<<grid, 256, 0, stream>>>(k, v, wskv, wsks);
    cf_out<<<grid, 256, 0, stream>>>(q, k, v, wskv, wsks, out);
}